// Round 3
// baseline (33.165 us; speedup 1.0000x reference)
//
#include <hip/hip_runtime.h>
#include <hip/hip_bf16.h>
#include <math.h>

#define EPS 1e-10f

typedef float floatx4 __attribute__((ext_vector_type(4)));

// Phase A: grid = S*B blocks of 256 threads. Block (seg,row) computes the
// argmax of its vocab segment for its row, writing (value, index) partials.
//   greedy row (t==0):  score = logits[j]
//   sampled row:        score = logits[j]*(1/t) - log(E[j]+EPS)
// (monotone-equivalent to softmax(logits/t)/(E+eps); log computed on the fly —
// it hides under the HBM-bound logits stream.)
__global__ __launch_bounds__(256) void partial_argmax_kernel(
    const float* __restrict__ logits,
    const float* __restrict__ temps,
    const float* __restrict__ expo,
    float* __restrict__ pv,   // [S*B] partial values
    int*   __restrict__ pi,   // [S*B] partial indices
    int B, int V, int segLen) {

    const int bid = blockIdx.x;
    const int row = bid % B;
    const int seg = bid / B;

    const float t = temps[row];                   // block-uniform
    const bool greedy = (t == 0.0f);
    const float inv_t = greedy ? 1.0f : (1.0f / t);

    const int beg4 = (seg * segLen) >> 2;         // segLen % 4 == 0
    int end4 = ((seg + 1) * segLen) >> 2;
    const int v4 = V >> 2;
    if (end4 > v4) end4 = v4;

    const floatx4* rl4 = reinterpret_cast<const floatx4*>(logits + (size_t)row * (size_t)V);
    const floatx4* e4  = reinterpret_cast<const floatx4*>(expo);

    float best = -INFINITY;
    int   bidx = 0x7fffffff;

    if (greedy) {
        for (int i = beg4 + threadIdx.x; i < end4; i += 256) {
            floatx4 l = __builtin_nontemporal_load(&rl4[i]);
            int base = i << 2;
            if (l.x > best) { best = l.x; bidx = base;     }
            if (l.y > best) { best = l.y; bidx = base + 1; }
            if (l.z > best) { best = l.z; bidx = base + 2; }
            if (l.w > best) { best = l.w; bidx = base + 3; }
        }
    } else {
        for (int i = beg4 + threadIdx.x; i < end4; i += 256) {
            floatx4 l = __builtin_nontemporal_load(&rl4[i]);
            floatx4 g = e4[i];
            float s0 = fmaf(l.x, inv_t, -logf(g.x + EPS));
            float s1 = fmaf(l.y, inv_t, -logf(g.y + EPS));
            float s2 = fmaf(l.z, inv_t, -logf(g.z + EPS));
            float s3 = fmaf(l.w, inv_t, -logf(g.w + EPS));
            int base = i << 2;
            if (s0 > best) { best = s0; bidx = base;     }
            if (s1 > best) { best = s1; bidx = base + 1; }
            if (s2 > best) { best = s2; bidx = base + 2; }
            if (s3 > best) { best = s3; bidx = base + 3; }
        }
    }

    // Wave reduce (64 lanes). Prefer lower index on exact ties.
    #pragma unroll
    for (int off = 32; off >= 1; off >>= 1) {
        float ov = __shfl_down(best, off);
        int   oi = __shfl_down(bidx, off);
        if (ov > best || (ov == best && oi < bidx)) { best = ov; bidx = oi; }
    }

    __shared__ float sv[4];
    __shared__ int   si[4];
    const int wid  = threadIdx.x >> 6;
    const int lane = threadIdx.x & 63;
    if (lane == 0) { sv[wid] = best; si[wid] = bidx; }
    __syncthreads();

    if (threadIdx.x == 0) {
        best = sv[0]; bidx = si[0];
        #pragma unroll
        for (int w = 1; w < 4; ++w) {
            if (sv[w] > best || (sv[w] == best && si[w] < bidx)) { best = sv[w]; bidx = si[w]; }
        }
        pv[bid] = best;
        pi[bid] = bidx;
    }
}

// Phase B: one block, thread r reduces the S partials of row r in ascending
// segment order (strict > == first-occurrence argmax).
__global__ __launch_bounds__(256) void final_reduce_kernel(
    const float* __restrict__ pv,
    const int*   __restrict__ pi,
    int* __restrict__ out,
    int B, int S) {
    const int r = threadIdx.x;
    if (r >= B) return;
    float best = pv[r];
    int   bidx = pi[r];
    for (int s = 1; s < S; ++s) {
        float v = pv[s * B + r];
        int   i = pi[s * B + r];
        if (v > best) { best = v; bidx = i; }
    }
    out[r] = bidx;
}

// Fallback (ws too small): one block per row, writes out directly.
__global__ __launch_bounds__(1024) void row_argmax_kernel(
    const float* __restrict__ logits,
    const float* __restrict__ temps,
    const float* __restrict__ expo,
    int* __restrict__ out, int V) {
    const int row = blockIdx.x;
    const float t = temps[row];
    const bool greedy = (t == 0.0f);
    const float inv_t = greedy ? 1.0f : (1.0f / t);
    const floatx4* rl4 = reinterpret_cast<const floatx4*>(logits + (size_t)row * (size_t)V);
    const floatx4* e4  = reinterpret_cast<const floatx4*>(expo);
    float best = -INFINITY; int bidx = 0x7fffffff;
    const int nvec = V >> 2;
    for (int i = threadIdx.x; i < nvec; i += blockDim.x) {
        floatx4 l = rl4[i];
        float s0, s1, s2, s3;
        if (greedy) { s0 = l.x; s1 = l.y; s2 = l.z; s3 = l.w; }
        else {
            floatx4 g = e4[i];
            s0 = fmaf(l.x, inv_t, -logf(g.x + EPS));
            s1 = fmaf(l.y, inv_t, -logf(g.y + EPS));
            s2 = fmaf(l.z, inv_t, -logf(g.z + EPS));
            s3 = fmaf(l.w, inv_t, -logf(g.w + EPS));
        }
        int base = i << 2;
        if (s0 > best) { best = s0; bidx = base;     }
        if (s1 > best) { best = s1; bidx = base + 1; }
        if (s2 > best) { best = s2; bidx = base + 2; }
        if (s3 > best) { best = s3; bidx = base + 3; }
    }
    #pragma unroll
    for (int off = 32; off >= 1; off >>= 1) {
        float ov = __shfl_down(best, off);
        int   oi = __shfl_down(bidx, off);
        if (ov > best || (ov == best && oi < bidx)) { best = ov; bidx = oi; }
    }
    __shared__ float sv[16];
    __shared__ int   si[16];
    const int wid = threadIdx.x >> 6, lane = threadIdx.x & 63, nw = blockDim.x >> 6;
    if (lane == 0) { sv[wid] = best; si[wid] = bidx; }
    __syncthreads();
    if (wid == 0) {
        best = (lane < nw) ? sv[lane] : -INFINITY;
        bidx = (lane < nw) ? si[lane] : 0x7fffffff;
        #pragma unroll
        for (int off = 8; off >= 1; off >>= 1) {
            float ov = __shfl_down(best, off);
            int   oi = __shfl_down(bidx, off);
            if (ov > best || (ov == best && oi < bidx)) { best = ov; bidx = oi; }
        }
        if (lane == 0) out[row] = bidx;
    }
}

extern "C" void kernel_launch(void* const* d_in, const int* in_sizes, int n_in,
                              void* d_out, int out_size, void* d_ws, size_t ws_size,
                              hipStream_t stream) {
    const float* logits = (const float*)d_in[0];
    const float* temps  = (const float*)d_in[1];
    const float* expo   = (const float*)d_in[2];
    int*         out    = (int*)d_out;

    const int B = in_sizes[1];
    const int V = in_sizes[2];

    const int S = 8;
    const int segLen = ((V + S - 1) / S + 3) & ~3;   // multiple of 4
    const size_t need = (size_t)S * B * (sizeof(float) + sizeof(int));

    if (ws_size >= need) {
        float* pv = (float*)d_ws;
        int*   pi = (int*)(pv + (size_t)S * B);
        partial_argmax_kernel<<<S * B, 256, 0, stream>>>(logits, temps, expo, pv, pi, B, V, segLen);
        final_reduce_kernel<<<1, 256, 0, stream>>>(pv, pi, out, B, S);
    } else {
        row_argmax_kernel<<<B, 1024, 0, stream>>>(logits, temps, expo, out, V);
    }
}